// Round 11
// baseline (98.413 us; speedup 1.0000x reference)
//
#include <hip/hip_runtime.h>
#include <hip/hip_bf16.h>

#define H 256
#define Wd 256
#define H2 128

typedef unsigned short ushort_t;
typedef __attribute__((ext_vector_type(8))) short short8;
typedef __attribute__((ext_vector_type(4))) float f32x4;

// guarded mish (k3: conv2 outputs can be larger; keep the clamp)
__device__ __forceinline__ float mishf(float v){
  if (v > 15.f) return v;
  float e = __expf(v);
  float w = e*(e+2.f);
  return v * w * __builtin_amdgcn_rcpf(w + 2.f);
}
// slim mish (conv1 outputs bounded -> no overflow possible)
__device__ __forceinline__ float mish_s(float v){
  float e = __expf(v);
  float w = e*(e+2.f);
  return v * w * __builtin_amdgcn_rcpf(w + 2.f);
}

__device__ __forceinline__ ushort_t f2bf(float f){
  unsigned int u = __float_as_uint(f);
  u += 0x7fffu + ((u >> 16) & 1u);
  return (ushort_t)(u >> 16);
}
__device__ __forceinline__ unsigned packbf(float a, float b){
  return (unsigned)f2bf(a) | ((unsigned)f2bf(b) << 16);
}
__device__ __forceinline__ float lo16(unsigned u){
  return __uint_as_float(u << 16);
}
__device__ __forceinline__ float hi16(unsigned u){
  return __uint_as_float(u & 0xffff0000u);
}

// ---------------------------------------------------------------------------
// shuf layout: 8-byte pixel records  [plane = b*16 + c][i*256 + j][m0..3]
// (bf16 x4). k12h writes top rows (own plane) and bottom rows (rolled plane).
// ---------------------------------------------------------------------------

// K0: pre-pack W2 into bf16 MFMA A-fragment order.
__global__ void k0_pack(const float* __restrict__ W2, ushort_t* __restrict__ wpack)
{
  int idx = blockIdx.x*128 + threadIdx.x;   // 0..1151
  if (idx >= 1152) return;
  int lane  = idx & 63;
  int s     = (idx >> 6) % 9;
  int khalf = idx / 576;
  int n = lane & 15, g = lane >> 4;
  unsigned int w[4];
#pragma unroll
  for (int h = 0; h < 4; ++h){
    int ch0 = khalf*32 + g*8 + 2*h;
    unsigned lo = f2bf(W2[(n*64 + ch0  )*9 + s]);
    unsigned hi = f2bf(W2[(n*64 + ch0+1)*9 + s]);
    w[h] = lo | (hi << 16);
  }
  *(uint4*)(wpack + (size_t)idx*8) = make_uint4(w[0], w[1], w[2], w[3]);
}

// ---------------------------------------------------------------------------
// K12H (v2): all global loads hoisted to kernel top (single vmcnt drain);
// ft tile quads padded to 48 B (2-way banks); one barrier.
//  Phase1: f_top once per 4-px quad (306 quads: A=tid, B=tid+256 for tid<50)
//  Phase2: f_bot in regs -> rolled-plane store + g
//  Phase4: span convs from LDS, o = g*A + B -> top store
// ---------------------------------------------------------------------------
#define QSTRIDE 48
#define RSTRIDE (17*QSTRIDE)   // 816 B per ft row
__global__ __launch_bounds__(256) void k12h(
    const float* __restrict__ x, const float* __restrict__ W1,
    const float* __restrict__ b1, const float* __restrict__ Wred,
    const float* __restrict__ bred, const float* __restrict__ Wspan,
    const float* __restrict__ bspan, ushort_t* __restrict__ shuf)
{
  __shared__ __align__(16) char ftl[18*RSTRIDE];   // ~14.3 KB

  int bid = blockIdx.x;             // 128 planes * 8 rowtiles * 4 coltiles
  int n   = bid >> 5;
  int t   = bid & 31;
  int itop0 = (t >> 2) * 16;
  int j0    = (t & 3) * 64;
  int tid = threadIdx.x;
  const float* xp = x + (size_t)n * (H*Wd);
  const float4 f4z = make_float4(0.f,0.f,0.f,0.f);

  float w1r[36], b1r[4], wsp[9], bsp[9], wredr[4];
  float bredr = bred[0];
#pragma unroll
  for (int k=0;k<36;k++) w1r[k] = W1[k];
#pragma unroll
  for (int m=0;m<4;m++){ b1r[m] = b1[m]; wredr[m] = Wred[m]; }
#pragma unroll
  for (int k=0;k<9;k++){ wsp[k] = Wspan[k]; bsp[k] = bspan[k]; }

  // ======== HOISTED LOADS (all global reads issued here) ========
  // Position A (always valid): pi = tid in [0,306)
  int pi  = tid;
  int rA  = pi / 17, qA = pi - rA*17;
  int frowA  = itop0 - 1 + rA;
  int fcA0 = j0 - 2 + 4*qA;
  bool okA = ((unsigned)frowA < 128u);
  float4 lA[3][2];
  {
    int cL = fcA0 - 2, cR = fcA0 + 2;
#pragma unroll
    for (int rr=0; rr<3; ++rr){
      int xr = frowA - 1 + rr;            // in [-1,128]
      bool rok = okA && (xr >= 0);
      const float* rp = xp + (size_t)xr*Wd;
      lA[rr][0] = (rok && cL >= 0)   ? *(const float4*)(rp + cL) : f4z;
      lA[rr][1] = (rok && cR <= 252) ? *(const float4*)(rp + cR) : f4z;
    }
  }
  // Position B (tid < 50): pi = tid + 256 in [256,306)
  bool hasB = (tid < 50);
  int piB = tid + 256;
  int rB  = piB / 17, qB = piB - rB*17;
  int frowB  = itop0 - 1 + rB;
  int fcB0 = j0 - 2 + 4*qB;
  bool okB = hasB && ((unsigned)frowB < 128u);
  float4 lB[3][2];
  {
    int cL = fcB0 - 2, cR = fcB0 + 2;
#pragma unroll
    for (int rr=0; rr<3; ++rr){
      int xr = frowB - 1 + rr;
      bool rok = okB && (xr >= 0);
      const float* rp = xp + (size_t)xr*Wd;
      lB[rr][0] = (rok && cL >= 0)   ? *(const float4*)(rp + cL) : f4z;
      lB[rr][1] = (rok && cR <= 252) ? *(const float4*)(rp + cR) : f4z;
    }
  }
  // Phase-2 window: x rows 127+trow..129+trow, cols jc-1..jc+4
  int lr  = tid >> 4;
  int lc4 = (tid & 15) * 4;
  int trow = itop0 + lr;
  int jc = j0 + lc4;
  float vb[3][6];
  {
    bool look = (jc >= 4);
    bool hiok = (jc <= 248);
#pragma unroll
    for (int rr=0; rr<3; ++rr){
      int xr = 127 + trow + rr;           // in [127,256]
      bool rok = (xr < 256);
      const float* rp = xp + (size_t)xr*Wd + jc;
      float4 m = rok ? *(const float4*)rp : f4z;
      float lw = (rok && look) ? rp[-1] : 0.f;
      float rw = (rok && hiok) ? rp[4]  : 0.f;
      vb[rr][0]=lw; vb[rr][1]=m.x; vb[rr][2]=m.y; vb[rr][3]=m.z; vb[rr][4]=m.w; vb[rr][5]=rw;
    }
  }

  // ======== Phase 1 compute: position A ========
#define FTQUAD(L_, frow_, fc0_, r_, q_, valid_) { \
    float s[4][4]; \
    _Pragma("unroll") \
    for (int m=0;m<4;m++) \
      _Pragma("unroll") \
      for (int p=0;p<4;p++) s[m][p] = b1r[m]; \
    float vrow[8]; \
    _Pragma("unroll") \
    for (int rr=0; rr<3; ++rr){ \
      vrow[0]=L_[rr][0].x; vrow[1]=L_[rr][0].y; vrow[2]=L_[rr][0].z; vrow[3]=L_[rr][0].w; \
      vrow[4]=L_[rr][1].x; vrow[5]=L_[rr][1].y; vrow[6]=L_[rr][1].z; vrow[7]=L_[rr][1].w; \
      _Pragma("unroll") \
      for (int kx=0;kx<3;kx++){ \
        _Pragma("unroll") \
        for (int m=0;m<4;m++){ \
          float wv = w1r[m*9+rr*3+kx]; \
          _Pragma("unroll") \
          for (int p=0;p<4;p++) \
            s[m][p] = fmaf(vrow[p+1+kx], wv, s[m][p]); \
        } \
      } \
    } \
    uint4 o0 = make_uint4(0u,0u,0u,0u), o1 = make_uint4(0u,0u,0u,0u); \
    if (valid_){ \
      unsigned pw[8]; \
      _Pragma("unroll") \
      for (int p=0;p<4;p++){ \
        bool ok = (unsigned)((fc0_)+p) < 256u; \
        pw[p*2]   = ok ? packbf(mish_s(s[0][p]), mish_s(s[1][p])) : 0u; \
        pw[p*2+1] = ok ? packbf(mish_s(s[2][p]), mish_s(s[3][p])) : 0u; \
      } \
      o0 = make_uint4(pw[0],pw[1],pw[2],pw[3]); \
      o1 = make_uint4(pw[4],pw[5],pw[6],pw[7]); \
    } \
    char* dst = ftl + (r_)*RSTRIDE + (q_)*QSTRIDE; \
    *(uint4*)dst = o0; \
    *(uint4*)(dst+16) = o1; \
  }

  FTQUAD(lA, frowA, fcA0, rA, qA, okA);
  if (hasB){ FTQUAD(lB, frowB, fcB0, rB, qB, okB); }

  // ======== Phase 2: f_bot + rolled store + g ========
  int bq = n >> 4, cq = n & 15;
  float fb[4][4];
#pragma unroll
  for (int m=0;m<4;m++)
#pragma unroll
    for (int p=0;p<4;p++){
      float s = b1r[m];
#pragma unroll
      for (int ky=0;ky<3;ky++)
#pragma unroll
        for (int kx=0;kx<3;kx++)
          s = fmaf(vb[ky][p+kx], w1r[m*9+ky*3+kx], s);
      fb[m][p] = mish_s(s);
    }
  int cdst = (cq + 15) & 15;
  size_t bbase = ((size_t)(bq*16 + cdst))*65536 + (size_t)(128+trow)*256 + jc;
  {
    unsigned w0 = packbf(fb[0][0], fb[1][0]), w1 = packbf(fb[2][0], fb[3][0]);
    unsigned w2 = packbf(fb[0][1], fb[1][1]), w3 = packbf(fb[2][1], fb[3][1]);
    *(uint4*)(shuf + bbase*4) = make_uint4(w0,w1,w2,w3);
    unsigned w4 = packbf(fb[0][2], fb[1][2]), w5 = packbf(fb[2][2], fb[3][2]);
    unsigned w6 = packbf(fb[0][3], fb[1][3]), w7 = packbf(fb[2][3], fb[3][3]);
    *(uint4*)(shuf + (bbase+2)*4) = make_uint4(w4,w5,w6,w7);
  }
  float gv[4];
#pragma unroll
  for (int p=0;p<4;p++){
    float s = bredr;
#pragma unroll
    for (int m=0;m<4;m++) s = fmaf(fb[m][p], wredr[m], s);
    gv[p] = fmaxf(s, 0.f);
  }

  __syncthreads();

  // ======== Phase 4: span convs from LDS ========
  float Aa[4][4], Bb[4][4];
#pragma unroll
  for (int m=0;m<4;m++)
#pragma unroll
    for (int p=0;p<4;p++){ Aa[m][p]=0.f; Bb[m][p]=0.f; }

  int kq = tid & 15;                  // quad index within row
#pragma unroll
  for (int ky=0;ky<3;ky++){
    const char* base = ftl + (lr+ky)*RSTRIDE;
    uint4 u0 = *(const uint4*)(base + kq*QSTRIDE);
    uint4 u1 = *(const uint4*)(base + kq*QSTRIDE + 16);
    uint4 u2 = *(const uint4*)(base + (kq+1)*QSTRIDE);
    uint4 u3 = *(const uint4*)(base + (kq+1)*QSTRIDE + 16);
    float f0[8], f1[8], f2[8], f3[8];
    f0[0]=lo16(u0.x); f1[0]=hi16(u0.x); f2[0]=lo16(u0.y); f3[0]=hi16(u0.y);
    f0[1]=lo16(u0.z); f1[1]=hi16(u0.z); f2[1]=lo16(u0.w); f3[1]=hi16(u0.w);
    f0[2]=lo16(u1.x); f1[2]=hi16(u1.x); f2[2]=lo16(u1.y); f3[2]=hi16(u1.y);
    f0[3]=lo16(u1.z); f1[3]=hi16(u1.z); f2[3]=lo16(u1.w); f3[3]=hi16(u1.w);
    f0[4]=lo16(u2.x); f1[4]=hi16(u2.x); f2[4]=lo16(u2.y); f3[4]=hi16(u2.y);
    f0[5]=lo16(u2.z); f1[5]=hi16(u2.z); f2[5]=lo16(u2.w); f3[5]=hi16(u2.w);
    f0[6]=lo16(u3.x); f1[6]=hi16(u3.x); f2[6]=lo16(u3.y); f3[6]=hi16(u3.y);
    f0[7]=lo16(u3.z); f1[7]=hi16(u3.z); f2[7]=lo16(u3.w); f3[7]=hi16(u3.w);
#pragma unroll
    for (int kx=0;kx<3;kx++){
      float ws = wsp[ky*3+kx], bs = bsp[ky*3+kx];
#pragma unroll
      for (int p=0;p<4;p++){
        int ix = p + 1 + kx;
        Aa[0][p] = fmaf(f0[ix], ws, Aa[0][p]); Bb[0][p] = fmaf(f0[ix], bs, Bb[0][p]);
        Aa[1][p] = fmaf(f1[ix], ws, Aa[1][p]); Bb[1][p] = fmaf(f1[ix], bs, Bb[1][p]);
        Aa[2][p] = fmaf(f2[ix], ws, Aa[2][p]); Bb[2][p] = fmaf(f2[ix], bs, Bb[2][p]);
        Aa[3][p] = fmaf(f3[ix], ws, Aa[3][p]); Bb[3][p] = fmaf(f3[ix], bs, Bb[3][p]);
      }
    }
  }

  float o[4][4];
#pragma unroll
  for (int m=0;m<4;m++)
#pragma unroll
    for (int p=0;p<4;p++)
      o[m][p] = fmaf(gv[p], Aa[m][p], Bb[m][p]);

  size_t pbase = ((size_t)(bq*16 + cq))*65536 + (size_t)trow*256 + jc;
  {
    unsigned w0 = packbf(o[0][0], o[1][0]), w1 = packbf(o[2][0], o[3][0]);
    unsigned w2 = packbf(o[0][1], o[1][1]), w3 = packbf(o[2][1], o[3][1]);
    *(uint4*)(shuf + pbase*4) = make_uint4(w0,w1,w2,w3);
    unsigned w4 = packbf(o[0][2], o[1][2]), w5 = packbf(o[2][2], o[3][2]);
    unsigned w6 = packbf(o[0][3], o[1][3]), w7 = packbf(o[2][3], o[3][3]);
    *(uint4*)(shuf + (pbase+2)*4) = make_uint4(w4,w5,w6,w7);
  }
#undef FTQUAD
}

// ---------------------------------------------------------------------------
// K3: conv2 via MFMA implicit GEMM, direct-from-global B fragments.
// ---------------------------------------------------------------------------
__global__ __launch_bounds__(256) void k3_conv2(
    const ushort_t* __restrict__ shuf, const ushort_t* __restrict__ wpack,
    const float* __restrict__ b2, float* __restrict__ scratch)
{
  __shared__ f32x4 mg[2][8][64];   // 16 KiB
  __shared__ float pacc[16];

  int bid0 = blockIdx.x;                     // 2048
  int bid  = (bid0 & 7)*256 + (bid0 >> 3);   // XCD-contiguous chunks
  int b   = bid >> 8;
  int t   = bid & 255;
  int rb  = t >> 3;
  int cb  = t & 7;
  int tid = threadIdx.x;
  int lane = tid & 63;
  int n = lane & 15;
  int g = lane >> 4;
  int wid = tid >> 6;
  int colhalf = wid & 1;
  int khalf   = wid >> 1;

  if (tid < 16) pacc[tid] = 0.f;

  const short8* wp = (const short8*)wpack + (size_t)khalf*576 + lane;
  short8 afr[9];
#pragma unroll
  for (int s = 0; s < 9; ++s) afr[s] = wp[s*64];

  f32x4 acc[8];
#pragma unroll
  for (int r = 0; r < 8; ++r) acc[r] = f32x4{0.f,0.f,0.f,0.f};

  int r0 = rb*8 - 1;
  int c  = cb*32 - 1 + colhalf*16 + n;
  int p0 = khalf*8 + g*2;
  const ushort_t* sp = shuf + ((size_t)(b*16 + p0))*262144;

#pragma unroll
  for (int hr = 0; hr < 10; ++hr){
    int grow = r0 + hr;
    bool rok = (unsigned)grow < 256u;
    uint2 va[3], vbv[3];
#pragma unroll
    for (int kx = 0; kx < 3; ++kx){
      int gcol = c + kx;
      uint2 a = make_uint2(0u,0u), bv = make_uint2(0u,0u);
      if (rok && (unsigned)gcol < 256u){
        const ushort_t* pp = sp + (size_t)(grow*256 + gcol)*4;
        a  = *(const uint2*)pp;
        bv = *(const uint2*)(pp + 262144);
      }
      va[kx] = a; vbv[kx] = bv;
    }
#pragma unroll
    for (int kx = 0; kx < 3; ++kx){
      union { uint4 u; short8 s; } cv;
      cv.u = make_uint4(va[kx].x, va[kx].y, vbv[kx].x, vbv[kx].y);
#pragma unroll
      for (int ky = 0; ky < 3; ++ky){
        int orow = hr - ky;
        if (orow >= 0 && orow < 8){
          acc[orow] = __builtin_amdgcn_mfma_f32_16x16x32_bf16(
              afr[ky*3+kx], cv.s, acc[orow], 0, 0, 0);
        }
      }
    }
  }

  if (khalf == 1){
#pragma unroll
    for (int r = 0; r < 8; ++r) mg[colhalf][r][lane] = acc[r];
  }
  __syncthreads();

  if (khalf == 0){
    float b2v[4];
#pragma unroll
    for (int q = 0; q < 4; ++q) b2v[q] = b2[g*4 + q];
    float po[4] = {0.f, 0.f, 0.f, 0.f};
#pragma unroll
    for (int r = 0; r < 8; ++r){
      f32x4 o = acc[r] + mg[colhalf][r][lane];
#pragma unroll
      for (int q = 0; q < 4; ++q) po[q] += mishf(o[q] + b2v[q]);
    }
#pragma unroll
    for (int q = 0; q < 4; ++q){
#pragma unroll
      for (int mk = 1; mk < 16; mk <<= 1) po[q] += __shfl_xor(po[q], mk);
    }
    if (n == 0){
#pragma unroll
      for (int q = 0; q < 4; ++q) atomicAdd(&pacc[g*4 + q], po[q]);
    }
  }
  __syncthreads();
  if (tid < 16) scratch[bid*16 + tid] = pacc[tid];
}

// K4: reduce per-block partials -> pooled mean -> ECA gate. One block per b.
__global__ void k4_gate(const float* __restrict__ scratch,
                        const float* __restrict__ Weca,
                        float* __restrict__ gate)
{
  __shared__ float rr[16][16];
  __shared__ float pool[16];
  int b = blockIdx.x;
  int t = threadIdx.x;           // 256
  int oc = t & 15, ch = t >> 4;
  float s = 0.f;
  for (int u = 0; u < 16; ++u)
    s += scratch[(size_t)(b*256 + ch*16 + u)*16 + oc];
  rr[ch][oc] = s;
  __syncthreads();
  if (t < 16){
    float tot = 0.f;
#pragma unroll
    for (int k = 0; k < 16; ++k) tot += rr[k][t];
    pool[t] = tot * (1.0f/65536.0f);
  }
  __syncthreads();
  if (t < 16){
    float pm = (t > 0)  ? pool[t-1] : 0.f;
    float p0 = pool[t];
    float pp = (t < 15) ? pool[t+1] : 0.f;
    float z = Weca[0]*pm + Weca[1]*p0 + Weca[2]*pp;
    gate[b*16 + t] = 1.f/(1.f + __expf(-z));
  }
}

// K5: out = x * gate[b,c], nontemporal load+store
__global__ __launch_bounds__(256) void k5_scale(
    const f32x4* __restrict__ x4, const float* __restrict__ gate,
    f32x4* __restrict__ out4)
{
  int idx = blockIdx.x*256 + threadIdx.x;
  float g = gate[idx >> 14];
  f32x4 v = __builtin_nontemporal_load(&x4[idx]) * g;
  __builtin_nontemporal_store(v, &out4[idx]);
}

extern "C" void kernel_launch(void* const* d_in, const int* in_sizes, int n_in,
                              void* d_out, int out_size, void* d_ws, size_t ws_size,
                              hipStream_t stream)
{
  const float* x     = (const float*)d_in[0];
  const float* W1    = (const float*)d_in[1];
  const float* b1    = (const float*)d_in[2];
  const float* Wred  = (const float*)d_in[3];
  const float* bred  = (const float*)d_in[4];
  const float* Wspan = (const float*)d_in[5];
  const float* bspan = (const float*)d_in[6];
  const float* W2    = (const float*)d_in[7];
  const float* b2    = (const float*)d_in[8];
  const float* Weca  = (const float*)d_in[9];

  ushort_t* shuf    = (ushort_t*)d_ws;                        // 64 MiB records
  float*    gate    = (float*)((char*)d_ws + 67108864);       // 512 B
  ushort_t* wpack   = (ushort_t*)((char*)d_ws + 67108864 + 1024); // 18.4 KiB
  float*    scratch = (float*)d_out;  // 2048*16 floats; overwritten by k5

  k0_pack<<<9, 128, 0, stream>>>(W2, wpack);
  k12h   <<<4096, 256, 0, stream>>>(x, W1, b1, Wred, bred, Wspan, bspan, shuf);
  k3_conv2<<<2048, 256, 0, stream>>>(shuf, wpack, b2, scratch);
  k4_gate<<<8, 256, 0, stream>>>(scratch, Weca, gate);
  k5_scale<<<8192, 256, 0, stream>>>((const f32x4*)x, gate, (f32x4*)d_out);
}

// Round 12
// 96.201 us; speedup vs baseline: 1.0230x; 1.0230x over previous
//
#include <hip/hip_runtime.h>
#include <hip/hip_bf16.h>

#define H 256
#define Wd 256
#define H2 128

typedef unsigned short ushort_t;
typedef __attribute__((ext_vector_type(8))) short short8;
typedef __attribute__((ext_vector_type(4))) float f32x4;

// guarded mish (k3: conv2 outputs can be larger; keep the clamp)
__device__ __forceinline__ float mishf(float v){
  if (v > 15.f) return v;
  float e = __expf(v);
  float w = e*(e+2.f);
  return v * w * __builtin_amdgcn_rcpf(w + 2.f);
}
// slim mish (conv1 outputs bounded -> no overflow possible)
__device__ __forceinline__ float mish_s(float v){
  float e = __expf(v);
  float w = e*(e+2.f);
  return v * w * __builtin_amdgcn_rcpf(w + 2.f);
}

__device__ __forceinline__ ushort_t f2bf(float f){
  unsigned int u = __float_as_uint(f);
  u += 0x7fffu + ((u >> 16) & 1u);
  return (ushort_t)(u >> 16);
}
__device__ __forceinline__ unsigned packbf(float a, float b){
  return (unsigned)f2bf(a) | ((unsigned)f2bf(b) << 16);
}
__device__ __forceinline__ float lo16(unsigned u){
  return __uint_as_float(u << 16);
}
__device__ __forceinline__ float hi16(unsigned u){
  return __uint_as_float(u & 0xffff0000u);
}

// ---------------------------------------------------------------------------
// shuf layout: 8-byte pixel records  [plane = b*16 + c][i*256 + j][m0..3]
// (bf16 x4). k12c writes top rows (own plane) and bottom rows (rolled plane).
// ---------------------------------------------------------------------------

// K0: pre-pack W2 into bf16 MFMA A-fragment order.
__global__ void k0_pack(const float* __restrict__ W2, ushort_t* __restrict__ wpack)
{
  int idx = blockIdx.x*128 + threadIdx.x;   // 0..1151
  if (idx >= 1152) return;
  int lane  = idx & 63;
  int s     = (idx >> 6) % 9;
  int khalf = idx / 576;
  int n = lane & 15, g = lane >> 4;
  unsigned int w[4];
#pragma unroll
  for (int h = 0; h < 4; ++h){
    int ch0 = khalf*32 + g*8 + 2*h;
    unsigned lo = f2bf(W2[(n*64 + ch0  )*9 + s]);
    unsigned hi = f2bf(W2[(n*64 + ch0+1)*9 + s]);
    w[h] = lo | (hi << 16);
  }
  *(uint4*)(wpack + (size_t)idx*8) = make_uint4(w[0], w[1], w[2], w[3]);
}

// ---------------------------------------------------------------------------
// K12C: column-sweep, register-only (NO LDS, NO barriers).
// Thread = 4 cols x 4 out rows. Rolling 3-row register windows for x and f.
// Bottom first (g in regs, rolled-plane store), then top sweep: 6 f-rows,
// each computed once, emit output row when 3 f-rows live. Span uses per-px
// combined weights wc = g*wsp + bsp (o = f (*) wc directly).
// ---------------------------------------------------------------------------
__global__ __launch_bounds__(256) void k12c(
    const float* __restrict__ x, const float* __restrict__ W1,
    const float* __restrict__ b1, const float* __restrict__ Wred,
    const float* __restrict__ bred, const float* __restrict__ Wspan,
    const float* __restrict__ bspan, ushort_t* __restrict__ shuf)
{
  int bid0 = blockIdx.x;                    // 1024
  int bid  = (bid0 & 7)*128 + (bid0 >> 3);  // plane-contiguous per XCD
  int n    = bid >> 3;                      // plane 0..127
  int L    = (bid & 7)*256 + threadIdx.x;   // 0..2047 within plane
  int band = L >> 6;                        // 0..31
  int strip= L & 63;                        // 0..63
  int r0 = band*4;                          // out rows r0..r0+3 (top)
  int jc = strip*4;
  const float* xp = x + (size_t)n*65536;
  bool jl = (jc == 0), jh = (jc == 252);
  int bq = n >> 4, cq = n & 15;
  const float4 f4z = make_float4(0.f,0.f,0.f,0.f);

  float w1r[36], b1r[4], wsp[9], bsp[9], wredr[4];
  float bredr = bred[0];
#pragma unroll
  for (int k=0;k<36;k++) w1r[k] = W1[k];
#pragma unroll
  for (int m=0;m<4;m++){ b1r[m] = b1[m]; wredr[m] = Wred[m]; }
#pragma unroll
  for (int k=0;k<9;k++){ wsp[k] = Wspan[k]; bsp[k] = bspan[k]; }

  // 6-wide row load (cols jc-1..jc+4), pred: row < 256
#define LOADB(row_, dst_) { \
    int rw = (row_); \
    bool rok = (rw < 256); \
    const float* rp = xp + rw*256 + jc; \
    float4 m_ = rok ? *(const float4*)rp : f4z; \
    float l_ = (rok && !jl) ? rp[-1] : 0.f; \
    float r_ = (rok && !jh) ? rp[4]  : 0.f; \
    dst_[0]=l_; dst_[1]=m_.x; dst_[2]=m_.y; dst_[3]=m_.z; dst_[4]=m_.w; dst_[5]=r_; }

  // 8-wide row load (cols jc-2..jc+5), pred: row >= 0
#define LOADT(row_, dst_) { \
    int rw = (row_); \
    bool rok = (rw >= 0); \
    const float* rp = xp + rw*256 + jc; \
    float4 m_ = rok ? *(const float4*)rp : f4z; \
    float4 l_ = (rok && !jl) ? *(const float4*)(rp-4) : f4z; \
    float4 r_ = (rok && !jh) ? *(const float4*)(rp+4) : f4z; \
    dst_[0]=l_.z; dst_[1]=l_.w; dst_[2]=m_.x; dst_[3]=m_.y; \
    dst_[4]=m_.z; dst_[5]=m_.w; dst_[6]=r_.x; dst_[7]=r_.y; }

  // ======== Bottom phase: rows 128+r0..131+r0 ========
  float gv[4][4];                           // [rr][px]
  {
    float xb[3][6];
    LOADB(127+r0, xb[0]);
    LOADB(128+r0, xb[1]);
    int cdst = (cq + 15) & 15;
    size_t bplane = ((size_t)(bq*16 + cdst))*65536;
#pragma unroll
    for (int rr=0; rr<4; ++rr){
      LOADB(129+r0+rr, xb[(rr+2)%3]);
      // x rows: br-1 -> xb[rr%3], br -> xb[(rr+1)%3], br+1 -> xb[(rr+2)%3]
      float fbv[4][4];                      // [m][px]
#pragma unroll
      for (int m=0;m<4;m++)
#pragma unroll
        for (int p=0;p<4;p++){
          float s = b1r[m];
#pragma unroll
          for (int ky=0;ky<3;ky++){
            const float* xr = xb[(rr+ky)%3];
#pragma unroll
            for (int kx=0;kx<3;kx++)
              s = fmaf(xr[p+kx], w1r[m*9+ky*3+kx], s);
          }
          fbv[m][p] = mish_s(s);
        }
      size_t base = bplane + (size_t)(128+r0+rr)*256 + jc;
      unsigned pw[8];
#pragma unroll
      for (int p=0;p<4;p++){
        pw[p*2]   = packbf(fbv[0][p], fbv[1][p]);
        pw[p*2+1] = packbf(fbv[2][p], fbv[3][p]);
      }
      *(uint4*)(shuf + base*4)     = make_uint4(pw[0],pw[1],pw[2],pw[3]);
      *(uint4*)(shuf + (base+2)*4) = make_uint4(pw[4],pw[5],pw[6],pw[7]);
#pragma unroll
      for (int p=0;p<4;p++){
        float s = bredr;
#pragma unroll
        for (int m=0;m<4;m++) s = fmaf(fbv[m][p], wredr[m], s);
        gv[rr][p] = fmaxf(s, 0.f);
      }
    }
  }

  // ======== Top phase: sweep f rows r0-1 .. r0+4, emit rows r0..r0+3 ========
  float xw[3][8];
  unsigned fw[3][6][2];                     // [rowslot][colslot][m01,m23]
  LOADT(r0-2, xw[0]);
  LOADT(r0-1, xw[1]);
  size_t tplane = (size_t)n*65536;

#pragma unroll
  for (int s=0; s<6; ++s){
    LOADT(r0+s, xw[(s+2)%3]);
    int fr = r0 - 1 + s;
    // x rows for f(fr): fr-1 -> xw[s%3], fr -> xw[(s+1)%3], fr+1 -> xw[(s+2)%3]
    if ((unsigned)fr < 128u){
#pragma unroll
      for (int cc=0; cc<6; ++cc){
        float s0 = b1r[0], s1 = b1r[1], s2 = b1r[2], s3 = b1r[3];
#pragma unroll
        for (int ky=0;ky<3;ky++){
          const float* xr = xw[(s+ky)%3];
#pragma unroll
          for (int kx=0;kx<3;kx++){
            float xv = xr[cc+kx];
            s0 = fmaf(xv, w1r[   ky*3+kx], s0);
            s1 = fmaf(xv, w1r[ 9+ky*3+kx], s1);
            s2 = fmaf(xv, w1r[18+ky*3+kx], s2);
            s3 = fmaf(xv, w1r[27+ky*3+kx], s3);
          }
        }
        fw[s%3][cc][0] = packbf(mish_s(s0), mish_s(s1));
        fw[s%3][cc][1] = packbf(mish_s(s2), mish_s(s3));
      }
      if (jl){ fw[s%3][0][0]=0u; fw[s%3][0][1]=0u; }
      if (jh){ fw[s%3][5][0]=0u; fw[s%3][5][1]=0u; }
    } else {
#pragma unroll
      for (int cc=0; cc<6; ++cc){ fw[s%3][cc][0]=0u; fw[s%3][cc][1]=0u; }
    }

    if (s >= 2){
      int orow = fr - 1;                    // r0 + (s-2)
      // f rows: orow-1 -> fw[(s-2)%3], orow -> fw[(s-1)%3], orow+1 -> fw[s%3]
      unsigned pw[8];
#pragma unroll
      for (int p=0;p<4;p++){
        float gvp = gv[s-2][p];
        float o0=0.f, o1=0.f, o2=0.f, o3=0.f;
#pragma unroll
        for (int ky=0;ky<3;ky++){
          const unsigned (*fr_)[2] = fw[(s-2+ky)%3];
#pragma unroll
          for (int kx=0;kx<3;kx++){
            float wc = fmaf(gvp, wsp[ky*3+kx], bsp[ky*3+kx]);
            unsigned u0 = fr_[p+kx][0], u1 = fr_[p+kx][1];
            o0 = fmaf(lo16(u0), wc, o0);
            o1 = fmaf(hi16(u0), wc, o1);
            o2 = fmaf(lo16(u1), wc, o2);
            o3 = fmaf(hi16(u1), wc, o3);
          }
        }
        pw[p*2]   = packbf(o0, o1);
        pw[p*2+1] = packbf(o2, o3);
      }
      size_t tbase = tplane + (size_t)orow*256 + jc;
      *(uint4*)(shuf + tbase*4)     = make_uint4(pw[0],pw[1],pw[2],pw[3]);
      *(uint4*)(shuf + (tbase+2)*4) = make_uint4(pw[4],pw[5],pw[6],pw[7]);
    }
  }
#undef LOADB
#undef LOADT
}

// ---------------------------------------------------------------------------
// K3: conv2 via MFMA implicit GEMM, direct-from-global B fragments.
// ---------------------------------------------------------------------------
__global__ __launch_bounds__(256) void k3_conv2(
    const ushort_t* __restrict__ shuf, const ushort_t* __restrict__ wpack,
    const float* __restrict__ b2, float* __restrict__ scratch)
{
  __shared__ f32x4 mg[2][8][64];   // 16 KiB
  __shared__ float pacc[16];

  int bid0 = blockIdx.x;                     // 2048
  int bid  = (bid0 & 7)*256 + (bid0 >> 3);   // XCD-contiguous chunks
  int b   = bid >> 8;
  int t   = bid & 255;
  int rb  = t >> 3;
  int cb  = t & 7;
  int tid = threadIdx.x;
  int lane = tid & 63;
  int n = lane & 15;
  int g = lane >> 4;
  int wid = tid >> 6;
  int colhalf = wid & 1;
  int khalf   = wid >> 1;

  if (tid < 16) pacc[tid] = 0.f;

  const short8* wp = (const short8*)wpack + (size_t)khalf*576 + lane;
  short8 afr[9];
#pragma unroll
  for (int s = 0; s < 9; ++s) afr[s] = wp[s*64];

  f32x4 acc[8];
#pragma unroll
  for (int r = 0; r < 8; ++r) acc[r] = f32x4{0.f,0.f,0.f,0.f};

  int r0 = rb*8 - 1;
  int c  = cb*32 - 1 + colhalf*16 + n;
  int p0 = khalf*8 + g*2;
  const ushort_t* sp = shuf + ((size_t)(b*16 + p0))*262144;

#pragma unroll
  for (int hr = 0; hr < 10; ++hr){
    int grow = r0 + hr;
    bool rok = (unsigned)grow < 256u;
    uint2 va[3], vbv[3];
#pragma unroll
    for (int kx = 0; kx < 3; ++kx){
      int gcol = c + kx;
      uint2 a = make_uint2(0u,0u), bv = make_uint2(0u,0u);
      if (rok && (unsigned)gcol < 256u){
        const ushort_t* pp = sp + (size_t)(grow*256 + gcol)*4;
        a  = *(const uint2*)pp;
        bv = *(const uint2*)(pp + 262144);
      }
      va[kx] = a; vbv[kx] = bv;
    }
#pragma unroll
    for (int kx = 0; kx < 3; ++kx){
      union { uint4 u; short8 s; } cv;
      cv.u = make_uint4(va[kx].x, va[kx].y, vbv[kx].x, vbv[kx].y);
#pragma unroll
      for (int ky = 0; ky < 3; ++ky){
        int orow = hr - ky;
        if (orow >= 0 && orow < 8){
          acc[orow] = __builtin_amdgcn_mfma_f32_16x16x32_bf16(
              afr[ky*3+kx], cv.s, acc[orow], 0, 0, 0);
        }
      }
    }
  }

  if (khalf == 1){
#pragma unroll
    for (int r = 0; r < 8; ++r) mg[colhalf][r][lane] = acc[r];
  }
  __syncthreads();

  if (khalf == 0){
    float b2v[4];
#pragma unroll
    for (int q = 0; q < 4; ++q) b2v[q] = b2[g*4 + q];
    float po[4] = {0.f, 0.f, 0.f, 0.f};
#pragma unroll
    for (int r = 0; r < 8; ++r){
      f32x4 o = acc[r] + mg[colhalf][r][lane];
#pragma unroll
      for (int q = 0; q < 4; ++q) po[q] += mishf(o[q] + b2v[q]);
    }
#pragma unroll
    for (int q = 0; q < 4; ++q){
#pragma unroll
      for (int mk = 1; mk < 16; mk <<= 1) po[q] += __shfl_xor(po[q], mk);
    }
    if (n == 0){
#pragma unroll
      for (int q = 0; q < 4; ++q) atomicAdd(&pacc[g*4 + q], po[q]);
    }
  }
  __syncthreads();
  if (tid < 16) scratch[bid*16 + tid] = pacc[tid];
}

// K4: reduce per-block partials -> pooled mean -> ECA gate. One block per b.
__global__ void k4_gate(const float* __restrict__ scratch,
                        const float* __restrict__ Weca,
                        float* __restrict__ gate)
{
  __shared__ float rr[16][16];
  __shared__ float pool[16];
  int b = blockIdx.x;
  int t = threadIdx.x;           // 256
  int oc = t & 15, ch = t >> 4;
  float s = 0.f;
  for (int u = 0; u < 16; ++u)
    s += scratch[(size_t)(b*256 + ch*16 + u)*16 + oc];
  rr[ch][oc] = s;
  __syncthreads();
  if (t < 16){
    float tot = 0.f;
#pragma unroll
    for (int k = 0; k < 16; ++k) tot += rr[k][t];
    pool[t] = tot * (1.0f/65536.0f);
  }
  __syncthreads();
  if (t < 16){
    float pm = (t > 0)  ? pool[t-1] : 0.f;
    float p0 = pool[t];
    float pp = (t < 15) ? pool[t+1] : 0.f;
    float z = Weca[0]*pm + Weca[1]*p0 + Weca[2]*pp;
    gate[b*16 + t] = 1.f/(1.f + __expf(-z));
  }
}

// K5: out = x * gate[b,c], nontemporal load+store
__global__ __launch_bounds__(256) void k5_scale(
    const f32x4* __restrict__ x4, const float* __restrict__ gate,
    f32x4* __restrict__ out4)
{
  int idx = blockIdx.x*256 + threadIdx.x;
  float g = gate[idx >> 14];
  f32x4 v = __builtin_nontemporal_load(&x4[idx]) * g;
  __builtin_nontemporal_store(v, &out4[idx]);
}

extern "C" void kernel_launch(void* const* d_in, const int* in_sizes, int n_in,
                              void* d_out, int out_size, void* d_ws, size_t ws_size,
                              hipStream_t stream)
{
  const float* x     = (const float*)d_in[0];
  const float* W1    = (const float*)d_in[1];
  const float* b1    = (const float*)d_in[2];
  const float* Wred  = (const float*)d_in[3];
  const float* bred  = (const float*)d_in[4];
  const float* Wspan = (const float*)d_in[5];
  const float* bspan = (const float*)d_in[6];
  const float* W2    = (const float*)d_in[7];
  const float* b2    = (const float*)d_in[8];
  const float* Weca  = (const float*)d_in[9];

  ushort_t* shuf    = (ushort_t*)d_ws;                        // 64 MiB records
  float*    gate    = (float*)((char*)d_ws + 67108864);       // 512 B
  ushort_t* wpack   = (ushort_t*)((char*)d_ws + 67108864 + 1024); // 18.4 KiB
  float*    scratch = (float*)d_out;  // 2048*16 floats; overwritten by k5

  k0_pack<<<9, 128, 0, stream>>>(W2, wpack);
  k12c   <<<1024, 256, 0, stream>>>(x, W1, b1, Wred, bred, Wspan, bspan, shuf);
  k3_conv2<<<2048, 256, 0, stream>>>(shuf, wpack, b2, scratch);
  k4_gate<<<8, 256, 0, stream>>>(scratch, Weca, gate);
  k5_scale<<<8192, 256, 0, stream>>>((const f32x4*)x, gate, (f32x4*)d_out);
}